// Round 5
// baseline (276.910 us; speedup 1.0000x reference)
//
#include <hip/hip_runtime.h>

// Problem constants (from reference setup_inputs)
constexpr int B  = 8;
constexpr int C  = 256;
constexpr int HW = 128 * 128;     // 16384 pixels per plane
constexpr int K  = 64;            // selected channels

// Native 4-float vector for __builtin_nontemporal_store (HIP's float4 is a
// class type the builtin rejects; this is layout-identical).
typedef float nfloat4 __attribute__((ext_vector_type(4)));

// Ranking-equivalent uncertainty:
//   u = -s*log(s+eps), s = sigmoid(v)
//   exact: u = s*log(1+e^-v) - eps  (uniform -eps shift -> rank-invariant;
//   positive constant factor 1/ln2 also rank-invariant, so use log2)
//   u' = log2(1+e^-v) * rcp(1+e^-v)
__device__ __forceinline__ float uncert_rank(float v) {
    float t = __expf(-v);
    float a = 1.0f + t;
    return __log2f(a) * __builtin_amdgcn_rcpf(a);
}

// Kernel 1: score[b,c] = rank-equivalent mean uncertainty over the plane.
// One block (256 threads) per (b,c) plane. BW-bound (~21 us for 134 MB).
// Normal (caching) loads on purpose: this pass makes x L3-resident for kernels 2-3.
__global__ __launch_bounds__(256) void score_kernel(const float* __restrict__ x,
                                                    float* __restrict__ score) {
    const int plane = blockIdx.x;                       // b*C + c
    const float4* xp = (const float4*)(x + (size_t)plane * HW);
    const int t = threadIdx.x;

    float acc = 0.0f;
#pragma unroll
    for (int i = 0; i < 16; ++i) {
        float4 v = xp[t + i * 256];
        acc += uncert_rank(v.x) + uncert_rank(v.y) + uncert_rank(v.z) + uncert_rank(v.w);
    }
#pragma unroll
    for (int off = 32; off > 0; off >>= 1) acc += __shfl_down(acc, off, 64);

    __shared__ float smem[4];
    if ((t & 63) == 0) smem[t >> 6] = acc;
    __syncthreads();
    if (t == 0) score[plane] = smem[0] + smem[1] + smem[2] + smem[3];  // scale rank-invariant
}

// Kernel 2 (topk + attn map): every block redundantly ranks the 256 channel
// scores from LDS (deterministic, ~1 us), then computes its 256-pixel chunk of
//   attn[b,p] = sigmoid(bias + sum_k w[k] * x[b, sel[k], p]).
// Selected-channel reads are L3 hits (x just loaded by score_kernel): 33.5 MB
// total ~ 2-4 us. Grid = B*64 = 512 blocks, 1 pixel/thread. No VGPR stash ->
// small register footprint, full occupancy.
__global__ __launch_bounds__(256) void attn_kernel(const float* __restrict__ x,
                                                   const float* __restrict__ score,
                                                   const float* __restrict__ w,
                                                   const float* __restrict__ bias,
                                                   float* __restrict__ attn) {
    const int b     = blockIdx.x >> 6;                  // 64 chunks per batch
    const int chunk = blockIdx.x & 63;                  // 256 pixels each
    const int t     = threadIdx.x;                      // also = channel for ranking

    __shared__ float sc[C];
    __shared__ float ws[K];
    __shared__ int   chs[K];                            // selected channel per rank

    sc[t] = score[b * C + t];
    if (t < K) ws[t] = w[t];
    __syncthreads();

    {   // exact rank with lax.top_k tie-break (lower index first)
        const float my = sc[t];
        int rank = 0;
#pragma unroll 8
        for (int j = 0; j < C; ++j) {
            float o = sc[j];
            rank += (o < my) || (o == my && j < t);
        }
        if (rank < K) chs[rank] = t;
    }
    __syncthreads();

    const int p = chunk * 256 + t;                      // pixel index in plane
    const float* xb = x + (size_t)b * C * HW;

    float a = 0.f;
#pragma unroll
    for (int k = 0; k < K; ++k) {
        a += ws[k] * xb[(size_t)chs[k] * HW + p];       // L3 hit
    }
    attn[b * HW + p] = __builtin_amdgcn_rcpf(1.0f + __expf(-(a + bias[0])));
}

// Kernel 3: out = x * attn, grid-stride float4 (16 B/lane), max occupancy.
// x reads are L3 hits; attn (512 KB unique) is L2-resident; out writes are
// NONTEMPORAL so the stream doesn't evict x from L3.
__global__ __launch_bounds__(256) void mul_kernel(const float* __restrict__ x,
                                                  const float* __restrict__ attn,
                                                  float* __restrict__ out) {
    const float4*  x4 = (const float4*)x;
    const float4*  a4 = (const float4*)attn;
    nfloat4*       o4 = (nfloat4*)out;
    constexpr size_t N4     = (size_t)B * C * HW / 4;   // 8388608 float4
    const size_t     stride = (size_t)gridDim.x * blockDim.x;

    for (size_t i = (size_t)blockIdx.x * blockDim.x + threadIdx.x; i < N4; i += stride) {
        float4 v = x4[i];
        // per-batch float4 count = C*HW/4 = 2^20; per-plane = 2^12
        float4 a = a4[((i >> 20) << 12) | (i & 4095)];
        nfloat4 o = {v.x * a.x, v.y * a.y, v.z * a.z, v.w * a.w};
        __builtin_nontemporal_store(o, &o4[i]);
    }
}

extern "C" void kernel_launch(void* const* d_in, const int* in_sizes, int n_in,
                              void* d_out, int out_size, void* d_ws, size_t ws_size,
                              hipStream_t stream) {
    const float* x    = (const float*)d_in[0];
    const float* w    = (const float*)d_in[1];
    const float* bias = (const float*)d_in[2];
    float* out = (float*)d_out;

    char* ws = (char*)d_ws;
    float* score = (float*)ws;                 // 2048 floats = 8 KiB
    float* attn  = (float*)(ws + 16384);       // B*HW floats = 512 KiB

    score_kernel<<<B * C, 256, 0, stream>>>(x, score);
    attn_kernel<<<B * 64, 256, 0, stream>>>(x, score, w, bias, attn);
    mul_kernel<<<2048, 256, 0, stream>>>(x, attn, out);
}

// Round 6
// 268.096 us; speedup vs baseline: 1.0329x; 1.0329x over previous
//
#include <hip/hip_runtime.h>

// Problem constants (from reference setup_inputs)
constexpr int B  = 8;
constexpr int C  = 256;
constexpr int HW = 128 * 128;     // 16384 pixels per plane
constexpr int K  = 64;            // selected channels
constexpr int U  = C - K;         // 192 unselected channels

// Ranking-equivalent uncertainty (rank-invariant transform of -s*log(s+eps)):
//   u' = log2(1+e^-v) * rcp(1+e^-v)
__device__ __forceinline__ float uncert_rank(float v) {
    float t = __expf(-v);
    float a = 1.0f + t;
    return __log2f(a) * __builtin_amdgcn_rcpf(a);
}

// Kernel 1: score[b,c] = rank-equivalent mean uncertainty over the plane.
// One block (256 threads) per (b,c) plane. BW-bound (~21 us for 134 MB).
__global__ __launch_bounds__(256) void score_kernel(const float* __restrict__ x,
                                                    float* __restrict__ score) {
    const int plane = blockIdx.x;                       // b*C + c
    const float4* xp = (const float4*)(x + (size_t)plane * HW);
    const int t = threadIdx.x;

    float acc = 0.0f;
#pragma unroll
    for (int i = 0; i < 16; ++i) {
        float4 v = xp[t + i * 256];
        acc += uncert_rank(v.x) + uncert_rank(v.y) + uncert_rank(v.z) + uncert_rank(v.w);
    }
#pragma unroll
    for (int off = 32; off > 0; off >>= 1) acc += __shfl_down(acc, off, 64);

    __shared__ float smem[4];
    if ((t & 63) == 0) smem[t >> 6] = acc;
    __syncthreads();
    if (t == 0) score[plane] = smem[0] + smem[1] + smem[2] + smem[3];  // scale rank-invariant
}

// Kernel 2: selection lists per batch, in ASCENDING channel order (better DRAM
// locality for the streaming kernel than rank order):
//   asel[b][i]   = i-th smallest selected channel      awt[b][i] = its conv weight
//   aunsel[b][i] = i-th smallest unselected channel
// Exact rank with lax.top_k tie-break (lower index first). Grid = B blocks.
__global__ __launch_bounds__(256) void select_kernel(const float* __restrict__ score,
                                                     const float* __restrict__ w,
                                                     int* __restrict__ asel,
                                                     float* __restrict__ awt,
                                                     int* __restrict__ aunsel) {
    const int b = blockIdx.x;
    const int t = threadIdx.x;                          // channel
    __shared__ float sc[C];
    __shared__ int   flagv[C];                          // 1 if selected
    __shared__ float wl[K];

    sc[t] = score[b * C + t];
    if (t < K) wl[t] = w[t];
    __syncthreads();

    const float my = sc[t];
    int rank = 0;
#pragma unroll 8
    for (int j = 0; j < C; ++j) {
        float o = sc[j];
        rank += (o < my) || (o == my && j < t);
    }
    const int selected = rank < K;
    flagv[t] = selected;
    __syncthreads();

    int pos = 0;                                        // ascending index within class
#pragma unroll 8
    for (int j = 0; j < C; ++j) pos += (j < t) && (flagv[j] == selected);

    if (selected) { asel[b * K + pos] = t; awt[b * K + pos] = wl[rank]; }
    else          { aunsel[b * U + pos] = t; }
}

// Kernel 3 (fused attn + multiply, channel-split for occupancy):
// TWO blocks share each 256-px chunk (h = 0/1). Both compute the full 64-channel
// attention sum (duplicated 33.5 MB of L3/HBM reads); each stores half:
//   - selected outputs for ascending positions [h*32, h*32+32) from a 32-reg stash
//   - unselected stream for channels aunsel[h*96 .. h*96+96)
// Grid = B * 64 chunks * 2 = 1024 blocks = 4 blocks/CU = 16 waves/CU (vs 8 before):
// doubles in-flight bytes for the latency-limited gather/stream. NT stores keep
// the write stream from evicting x from L3.
__global__ __launch_bounds__(256, 4) void attn_mul_kernel(const float* __restrict__ x,
                                                          const int* __restrict__ asel,
                                                          const float* __restrict__ awt,
                                                          const int* __restrict__ aunsel,
                                                          const float* __restrict__ bias,
                                                          float* __restrict__ out) {
    const int b     = blockIdx.x >> 7;                  // 128 blocks per batch
    const int r     = blockIdx.x & 127;
    const int chunk = r >> 1;                           // 64 chunks of 256 px
    const int h     = r & 1;                            // half index
    const int t     = threadIdx.x;

    __shared__ int   chs[K];
    __shared__ float wk[K];
    __shared__ int   un[U];
    if (t < K) { chs[t] = asel[b * K + t]; wk[t] = awt[b * K + t]; }
    if (t < U) { un[t]  = aunsel[b * U + t]; }
    __syncthreads();

    const int p = chunk * 256 + t;                      // pixel index in plane
    const float* xb = x + (size_t)b * C * HW;
    float*       ob = out + (size_t)b * C * HW;

    // Phase A: full weighted sum over 64 selected channels (ascending order),
    // stashing the 32 values this half will store (static register indices;
    // the h-conditional compiles to cndmask selects).
    float st[K / 2];
    float a = 0.f;
#pragma unroll
    for (int k = 0; k < K; ++k) {
        float v = xb[(size_t)chs[k] * HW + p];
        if ((k >> 5) == h) st[k & 31] = v;
        a += wk[k] * v;
    }
    const float sg = __builtin_amdgcn_rcpf(1.0f + __expf(-(a + bias[0])));  // sigmoid

    // Phase A': this half's 32 selected-channel outputs from the stash.
#pragma unroll
    for (int j = 0; j < K / 2; ++j) {
        __builtin_nontemporal_store(st[j] * sg, &ob[(size_t)chs[h * 32 + j] * HW + p]);
    }

    // Phase B: stream this half's 96 unselected channels (ascending order).
    const int jb = h * 96;
#pragma unroll 16
    for (int j = 0; j < U / 2; ++j) {
        const size_t idx = (size_t)un[jb + j] * HW + p;
        __builtin_nontemporal_store(xb[idx] * sg, &ob[idx]);
    }
}

extern "C" void kernel_launch(void* const* d_in, const int* in_sizes, int n_in,
                              void* d_out, int out_size, void* d_ws, size_t ws_size,
                              hipStream_t stream) {
    const float* x    = (const float*)d_in[0];
    const float* w    = (const float*)d_in[1];
    const float* bias = (const float*)d_in[2];
    float* out = (float*)d_out;

    char* ws = (char*)d_ws;
    float* score  = (float*)ws;                 // 2048 f  = 8 KiB   @ 0
    int*   asel   = (int*)(ws + 8192);          // 512 i   = 2 KiB   @ 8K
    float* awt    = (float*)(ws + 10240);       // 512 f   = 2 KiB   @ 10K
    int*   aunsel = (int*)(ws + 12288);         // 1536 i  = 6 KiB   @ 12K

    score_kernel<<<B * C, 256, 0, stream>>>(x, score);
    select_kernel<<<B, 256, 0, stream>>>(score, w, asel, awt, aunsel);
    attn_mul_kernel<<<B * 128, 256, 0, stream>>>(x, asel, awt, aunsel, bias, out);
}

// Round 8
// 257.534 us; speedup vs baseline: 1.0752x; 1.0410x over previous
//
#include <hip/hip_runtime.h>

// Problem constants (from reference setup_inputs)
constexpr int B  = 8;
constexpr int C  = 256;
constexpr int HW = 128 * 128;     // 16384 pixels per plane
constexpr int K  = 64;            // selected channels

// Ranking-equivalent uncertainty:
//   u = -s*log(s+eps), s = sigmoid(v)
//   exact: u = s*log(1+e^-v) - eps  (the -eps is a uniform shift -> rank-invariant;
//   positive constant factor 1/ln2 also rank-invariant, so use log2)
//   u' = log2(1+e^-v) * rcp(1+e^-v)
__device__ __forceinline__ float uncert_rank(float v) {
    float t = __expf(-v);
    float a = 1.0f + t;
    return __log2f(a) * __builtin_amdgcn_rcpf(a);
}

// Kernel 1: score[b,c] = rank-equivalent mean uncertainty over the plane.
// One block (256 threads) per (b,c) plane. BW-bound.
__global__ __launch_bounds__(256) void score_kernel(const float* __restrict__ x,
                                                    float* __restrict__ score) {
    const int plane = blockIdx.x;                       // b*C + c
    const float4* xp = (const float4*)(x + (size_t)plane * HW);
    const int t = threadIdx.x;

    float acc = 0.0f;
#pragma unroll
    for (int i = 0; i < 16; ++i) {
        float4 v = xp[t + i * 256];
        acc += uncert_rank(v.x) + uncert_rank(v.y) + uncert_rank(v.z) + uncert_rank(v.w);
    }
#pragma unroll
    for (int off = 32; off > 0; off >>= 1) acc += __shfl_down(acc, off, 64);

    __shared__ float smem[4];
    if ((t & 63) == 0) smem[t >> 6] = acc;
    __syncthreads();
    if (t == 0) score[plane] = smem[0] + smem[1] + smem[2] + smem[3];  // scale rank-invariant
}

// Kernel 2 (fused topk + attn + multiply), traffic = 1 read of x + 1 write of out:
//  - every block redundantly ranks the 256 channel scores (deterministic, ~1 us)
//  - Phase A: read the 64 selected channels once; STASH in 64 VGPRs while
//    accumulating the weighted sum; attn = sigmoid(sum + bias) stays in a register
//  - Phase A': selected-channel outputs written from the stash (no re-read)
//  - Phase B: stream the 192 unselected channels
// Grid = B*64 = 512 blocks (2/CU -> 8 waves/CU), 256 threads, 1 pixel per thread.
// __launch_bounds__(256,2) caps VGPR at 256; stash(64)+misc ~= 110, no spill.
// NT stores keep the out-stream from evicting x from L3.
__global__ __launch_bounds__(256, 2) void attn_mul_kernel(const float* __restrict__ x,
                                                          const float* __restrict__ score,
                                                          const float* __restrict__ w,
                                                          const float* __restrict__ bias,
                                                          float* __restrict__ out) {
    const int b     = blockIdx.x >> 6;                  // 64 chunks per batch
    const int chunk = blockIdx.x & 63;                  // 256 pixels each
    const int t     = threadIdx.x;                      // also = channel for ranking

    __shared__ float sc[C];
    __shared__ float ws[K];
    __shared__ int   chs[K];                            // selected channel per rank
    __shared__ int   unch[C - K];                       // unselected channels

    sc[t] = score[b * C + t];
    if (t < K) ws[t] = w[t];
    __syncthreads();

    {   // exact rank with lax.top_k tie-break (lower index first)
        const float my = sc[t];
        int rank = 0;
#pragma unroll 8
        for (int j = 0; j < C; ++j) {
            float o = sc[j];
            rank += (o < my) || (o == my && j < t);
        }
        if (rank < K) chs[rank] = t;
        else          unch[rank - K] = t;
    }
    __syncthreads();

    const int p = chunk * 256 + t;                      // pixel index in plane
    const float* xb = x + (size_t)b * C * HW;
    float*       ob = out + (size_t)b * C * HW;

    // Phase A: weighted sum over the 64 selected channels, stashing values
    // (fully unrolled -> static register indices, no scratch).
    float st[K];
    float a = 0.f;
#pragma unroll
    for (int k = 0; k < K; ++k) {
        float v = xb[(size_t)chs[k] * HW + p];
        st[k] = v;
        a += ws[k] * v;
    }
    const float sg = __builtin_amdgcn_rcpf(1.0f + __expf(-(a + bias[0])));  // sigmoid

    // Phase A': selected-channel outputs from the stash — no re-read of x.
#pragma unroll
    for (int k = 0; k < K; ++k) {
        __builtin_nontemporal_store(st[k] * sg, &ob[(size_t)chs[k] * HW + p]);
    }

    // Phase B: stream the 192 unselected channels.
#pragma unroll 8
    for (int j = 0; j < C - K; ++j) {
        const size_t idx = (size_t)unch[j] * HW + p;
        __builtin_nontemporal_store(xb[idx] * sg, &ob[idx]);
    }
}

extern "C" void kernel_launch(void* const* d_in, const int* in_sizes, int n_in,
                              void* d_out, int out_size, void* d_ws, size_t ws_size,
                              hipStream_t stream) {
    const float* x    = (const float*)d_in[0];
    const float* w    = (const float*)d_in[1];
    const float* bias = (const float*)d_in[2];
    float* out = (float*)d_out;

    float* score = (float*)d_ws;               // 2048 floats = 8 KiB

    score_kernel<<<B * C, 256, 0, stream>>>(x, score);
    attn_mul_kernel<<<B * 64, 256, 0, stream>>>(x, score, w, bias, out);
}